// Round 10
// baseline (147.728 us; speedup 1.0000x reference)
//
#include <hip/hip_runtime.h>
#include <hip/hip_bf16.h>
#include <math.h>

#define B_ 8
#define S_ 4096
#define C_ 64
#define EPSV 1e-5f

using floatx4 = __attribute__((ext_vector_type(4))) float;
using bf16x8  = __attribute__((ext_vector_type(8))) short;
using bf16x4  = __attribute__((ext_vector_type(4))) short;

typedef __attribute__((address_space(3))) unsigned int       as3_u32;
typedef __attribute__((address_space(1))) const unsigned int as1_u32;

__device__ __forceinline__ short f2bf(float f) {
    unsigned u = __builtin_bit_cast(unsigned, f);
    u = u + 0x7fffu + ((u >> 16) & 1u);   // RNE
    return (short)(u >> 16);
}

__device__ __forceinline__ unsigned cvt_pk_bf16(float lo, float hi) {
    unsigned r;
    asm volatile("v_cvt_pk_bf16_f32 %0, %1, %2" : "=v"(r) : "v"(lo), "v"(hi));
    return r;
}

// PV MFMA: 16x16x16 bf16 (K=16) — B-fragment layout (col=c, k=4g+j) matches
// the swapped-QK^T accumulator layout directly -> no cross-lane redistribution.
__device__ __forceinline__ floatx4 mfma_16x16x16_bf16(bf16x4 a, bf16x4 b, floatx4 c) {
#if __has_builtin(__builtin_amdgcn_mfma_f32_16x16x16bf16_1k)
    return __builtin_amdgcn_mfma_f32_16x16x16bf16_1k(a, b, c, 0, 0, 0);
#else
    asm("v_mfma_f32_16x16x16_bf16 %0, %1, %2, %0" : "+v"(c) : "v"(a), "v"(b));
    return c;
#endif
}

// B-fragment from a row-major fp32 64x64 weight matrix.
__device__ __forceinline__ bf16x8 ld_w_frag(const float* __restrict__ W, int n, int kk, int g, int c) {
    const float* p = W + (16 * n + c) * C_ + 32 * kk + 8 * g;
    bf16x8 r;
#pragma unroll
    for (int j = 0; j < 8; ++j) r[j] = f2bf(p[j]);
    return r;
}

// ---------------- kernel 1a: per-chunk partial sums ----------------
__global__ __launch_bounds__(256) void stats1_kernel(const float* __restrict__ x,
                                                     float* __restrict__ partial) {
    int b = blockIdx.x >> 5, chunk = blockIdx.x & 31;
    const float4* xb = (const float4*)x + (size_t)b * 65536 + chunk * 2048;
    float s = 0.f, ss = 0.f;
#pragma unroll
    for (int i = 0; i < 8; ++i) {
        float4 v = xb[threadIdx.x + i * 256];
        s  += v.x + v.y + v.z + v.w;
        ss += v.x * v.x + v.y * v.y + v.z * v.z + v.w * v.w;
    }
    for (int off = 32; off > 0; off >>= 1) {
        s  += __shfl_down(s, off);
        ss += __shfl_down(ss, off);
    }
    __shared__ float sm[4], ssm[4];
    int wid = threadIdx.x >> 6, lane = threadIdx.x & 63;
    if (lane == 0) { sm[wid] = s; ssm[wid] = ss; }
    __syncthreads();
    if (threadIdx.x == 0) {
        partial[blockIdx.x * 2]     = sm[0] + sm[1] + sm[2] + sm[3];
        partial[blockIdx.x * 2 + 1] = ssm[0] + ssm[1] + ssm[2] + ssm[3];
    }
}

// ---------------- kernel 1b: finalize mean / rsqrt(var) ----------------
__global__ __launch_bounds__(512) void stats2_kernel(const float* __restrict__ partial,
                                                     float* __restrict__ stats) {
    int w = threadIdx.x >> 6, lane = threadIdx.x & 63;  // wave w = batch w
    float s = 0.f, ss = 0.f;
    if (lane < 32) {
        s  = partial[(w * 32 + lane) * 2];
        ss = partial[(w * 32 + lane) * 2 + 1];
    }
    for (int off = 16; off > 0; off >>= 1) {
        s  += __shfl_down(s, off);
        ss += __shfl_down(ss, off);
    }
    if (lane == 0) {
        const float invN = 1.0f / (float)(S_ * C_);
        float mu  = s * invN;
        float var = ss * invN - mu * mu;
        stats[w * 2]     = mu;
        stats[w * 2 + 1] = rsqrtf(var + EPSV);
    }
}

// ---------------- kernel 2: normalize + Q/K/V^T projections ----------------
// K and V^T are written as per-64-kv TILE IMAGES (8192 B each), XOR-swizzled
// exactly as the flash kernel's LDS wants them (both-sides rule).
//   K tile:  [64 kv-rows][64 ch] bf16, byte = (r*128 + ch*2) ^ ((r&7)<<4)
//   V tile:  [64 ch-rows][64 kv] bf16, byte = (ch*128 + u*2) ^ ((ch&7)<<4)
__global__ __launch_bounds__(256) void proj_kernel(
    const float* __restrict__ x,
    const float* __restrict__ Wq, const float* __restrict__ bq,
    const float* __restrict__ Wk, const float* __restrict__ bk,
    const float* __restrict__ Wv, const float* __restrict__ bv,
    const float* __restrict__ stats,
    short* __restrict__ qo, char* __restrict__ kws, char* __restrict__ vws) {
    __shared__ char hbuf[64 * 128];  // [64 rows][64 bf16], XOR-swizzled

    int b  = blockIdx.x >> 6;
    int t_ = blockIdx.x & 63;        // 64-row tile index within batch
    int s0 = t_ * 64;
    float mu = stats[b * 2], rs = stats[b * 2 + 1];
    const float* xt = x + ((size_t)b * S_ + s0) * C_;
    int t = threadIdx.x;

#pragma unroll
    for (int i = 0; i < 4; ++i) {
        int fi  = t + 256 * i;       // float4 index within 64x64 tile
        int row = fi >> 4;
        int c4  = fi & 15;
        float4 v = *(const float4*)(xt + row * C_ + c4 * 4);
        unsigned lo = (unsigned)(unsigned short)f2bf((v.x - mu) * rs) |
                      ((unsigned)(unsigned short)f2bf((v.y - mu) * rs) << 16);
        unsigned hi = (unsigned)(unsigned short)f2bf((v.z - mu) * rs) |
                      ((unsigned)(unsigned short)f2bf((v.w - mu) * rs) << 16);
        int off = row * 128 + c4 * 8;
        off ^= (row & 7) << 4;
        *(uint2*)(hbuf + off) = make_uint2(lo, hi);
    }
    __syncthreads();

    int lane = t & 63, w = t >> 6;
    int g = lane >> 4, c = lane & 15;

    auto ld_h = [&](int row, int kcol) -> bf16x8 {
        int off = row * 128 + kcol * 2;
        off ^= (row & 7) << 4;
        return *(const bf16x8*)(hbuf + off);
    };

    size_t tilebase = ((size_t)b * 64 + t_) * 8192;

    // ---- Q and K: D = h @ W^T.  A = h rows 16w..16w+15 ----
    bf16x8 ha[2];
    ha[0] = ld_h(16 * w + c, 8 * g);
    ha[1] = ld_h(16 * w + c, 32 + 8 * g);

    const float QSC = 0.125f * 1.44269504088896340736f;  // C^-0.5 * log2(e)

#pragma unroll
    for (int n = 0; n < 4; ++n) {
        floatx4 aq = {0.f, 0.f, 0.f, 0.f}, ak = {0.f, 0.f, 0.f, 0.f};
#pragma unroll
        for (int kk = 0; kk < 2; ++kk) {
            bf16x8 wq = ld_w_frag(Wq, n, kk, g, c);
            bf16x8 wk = ld_w_frag(Wk, n, kk, g, c);
            aq = __builtin_amdgcn_mfma_f32_16x16x32_bf16(ha[kk], wq, aq, 0, 0, 0);
            ak = __builtin_amdgcn_mfma_f32_16x16x32_bf16(ha[kk], wk, ak, 0, 0, 0);
        }
        float bqv = bq[16 * n + c], bkv = bk[16 * n + c];
#pragma unroll
        for (int r = 0; r < 4; ++r) {
            int rr = 16 * w + 4 * g + r;          // kv row within tile
            qo[((size_t)b * S_ + s0 + rr) * C_ + 16 * n + c] = f2bf((aq[r] + bqv) * QSC);
            int koff = (rr * 128 + (16 * n + c) * 2) ^ ((rr & 7) << 4);
            *(short*)(kws + tilebase + koff) = f2bf(ak[r] + bkv);
        }
    }

    // ---- V^T = Wv @ h^T (direct transposed, swizzled tile image) ----
    bf16x8 wv[2];
    wv[0] = ld_w_frag(Wv, w, 0, g, c);
    wv[1] = ld_w_frag(Wv, w, 1, g, c);
    float bvr[4];
#pragma unroll
    for (int r = 0; r < 4; ++r) bvr[r] = bv[16 * w + 4 * g + r];

#pragma unroll
    for (int n = 0; n < 4; ++n) {
        floatx4 av = {0.f, 0.f, 0.f, 0.f};
#pragma unroll
        for (int kk = 0; kk < 2; ++kk) {
            bf16x8 hb = ld_h(16 * n + c, 32 * kk + 8 * g);
            av = __builtin_amdgcn_mfma_f32_16x16x32_bf16(wv[kk], hb, av, 0, 0, 0);
        }
#pragma unroll
        for (int r = 0; r < 4; ++r) {
            int rr = 16 * w + 4 * g + r;          // channel row
            int u  = 16 * n + c;                  // kv col within tile
            int voff = (rr * 128 + u * 2) ^ ((rr & 7) << 4);
            *(short*)(vws + tilebase + voff) = f2bf(av[r] + bvr[r]);
        }
    }
}

// ---------------- kernel 3: wave-sliced, software-pipelined flash attention ----------------
// Block = 64 q rows. Wave w owns kv rows 16w..16w+15 of every staged tile.
// Triple-buffered: iter t stages tile t+2, computes QK(t+1) BEFORE softmax(t)
// so MFMA overlaps the softmax VALU chain within the wave. l is accumulated by
// a ones-fragment MFMA (off the VALU critical path).
__global__ __launch_bounds__(256) void flash_kernel(
    const short* __restrict__ qm, const char* __restrict__ kws, const char* __restrict__ vws,
    const float* __restrict__ Wo, const float* __restrict__ bo,
    const float* __restrict__ x, float* __restrict__ out) {
    __shared__ char kb[3][8192];
    __shared__ char vb[3][8192];
    __shared__ float buf[64][68];      // combined O (q rows, ch cols)
    __shared__ float mlb[4][2][64];    // per-wave m,l per q
    __shared__ float Lq[64];           // final denominators

    int bid = blockIdx.x;
    int logical = (bid & 7) * 64 + (bid >> 3);  // XCD swizzle: batch b -> XCD b
    int b = logical >> 6;
    int q0 = (logical & 63) * 64;
    int t = threadIdx.x;
    int lane = t & 63, w = t >> 6;
    int g = lane >> 4, c = lane & 15;

    const char* kbase = kws + (size_t)b * 64 * 8192;
    const char* vbase = vws + (size_t)b * 64 * 8192;
    const short* qp = qm + (size_t)b * S_ * C_;

    // Q^T B-fragments for ALL 64 q rows (4 subtiles), held in regs.
    bf16x8 bqf[4][2];
#pragma unroll
    for (int qi = 0; qi < 4; ++qi) {
        bqf[qi][0] = *(const bf16x8*)(qp + (q0 + 16 * qi + c) * C_ + 8 * g);
        bqf[qi][1] = *(const bf16x8*)(qp + (q0 + 16 * qi + c) * C_ + 32 + 8 * g);
    }

    floatx4 oacc[4][4];                // [mi(ch)][qi]
#pragma unroll
    for (int mi = 0; mi < 4; ++mi)
#pragma unroll
        for (int qi = 0; qi < 4; ++qi) oacc[mi][qi] = (floatx4){0.f, 0.f, 0.f, 0.f};
    floatx4 l_acc[4];                  // l via ones-MFMA; use elem 0
#pragma unroll
    for (int qi = 0; qi < 4; ++qi) l_acc[qi] = (floatx4){0.f, 0.f, 0.f, 0.f};
    float m[4];
#pragma unroll
    for (int qi = 0; qi < 4; ++qi) m[qi] = -__builtin_inff();

    const bf16x4 vones = {(short)0x3F80, (short)0x3F80, (short)0x3F80, (short)0x3F80};
    const int xmask = (c & 7) << 4;   // per-lane row-swizzle mask (bits 4-6)
    const int krd = w * 2048 + c * 128;              // K slice base (row 16w+c)
    const int vrd = c * 128 + ((32 * w + 8 * g) ^ xmask);  // V slice col base

    auto STAGE = [&](char* lk, char* lv, int tt) {
        const char* gk = kbase + (size_t)tt * 8192 + w * 2048 + lane * 16;
        const char* gv = vbase + (size_t)tt * 8192 + w * 2048 + lane * 16;
        lk += w * 2048; lv += w * 2048;
        __builtin_amdgcn_global_load_lds((as1_u32*)gk,          (as3_u32*)lk,          16, 0, 0);
        __builtin_amdgcn_global_load_lds((as1_u32*)(gk + 1024), (as3_u32*)(lk + 1024), 16, 0, 0);
        __builtin_amdgcn_global_load_lds((as1_u32*)gv,          (as3_u32*)lv,          16, 0, 0);
        __builtin_amdgcn_global_load_lds((as1_u32*)(gv + 1024), (as3_u32*)(lv + 1024), 16, 0, 0);
    };

    auto QK = [&](const char* kbuf, floatx4 (&st)[4]) {
        bf16x8 ak0 = *(const bf16x8*)(kbuf + krd + ((16 * g) ^ xmask));
        bf16x8 ak1 = *(const bf16x8*)(kbuf + krd + ((64 + 16 * g) ^ xmask));
        __builtin_amdgcn_s_setprio(1);
#pragma unroll
        for (int qi = 0; qi < 4; ++qi) {
            st[qi] = (floatx4){0.f, 0.f, 0.f, 0.f};
            st[qi] = __builtin_amdgcn_mfma_f32_16x16x32_bf16(ak0, bqf[qi][0], st[qi], 0, 0, 0);
            st[qi] = __builtin_amdgcn_mfma_f32_16x16x32_bf16(ak1, bqf[qi][1], st[qi], 0, 0, 0);
        }
        __builtin_amdgcn_s_setprio(0);
    };

    char *kcur = kb[0], *knxt = kb[1], *kstg = kb[2];
    char *vcur = vb[0], *vnxt = vb[1], *vstg = vb[2];

    STAGE(kcur, vcur, 0);
    STAGE(knxt, vnxt, 1);
    __syncthreads();

    floatx4 st[4];
    QK(kcur, st);

    for (int tt = 0; tt < 64; ++tt) {
        if (tt < 62) STAGE(kstg, vstg, tt + 2);
        // QK for NEXT tile first — independent of softmax(st) -> ILP
        floatx4 stn[4];
        if (tt < 63) QK(knxt, stn);
        // V slice reads (independent of softmax) issued early
        bf16x4 av[4];
#pragma unroll
        for (int mi = 0; mi < 4; ++mi)
            av[mi] = *(const bf16x4*)(vcur + mi * 2048 + vrd);

        // ---- online softmax on st (tile tt); single rescale branch ----
        float mt[4], need = -1e30f;
#pragma unroll
        for (int qi = 0; qi < 4; ++qi) {
            float v = fmaxf(fmaxf(st[qi][0], st[qi][1]), fmaxf(st[qi][2], st[qi][3]));
            v = fmaxf(v, __shfl_xor(v, 16));
            v = fmaxf(v, __shfl_xor(v, 32));
            mt[qi] = v;
            need = fmaxf(need, v - m[qi]);
        }
        if (!__all(need <= 8.0f)) {
#pragma unroll
            for (int qi = 0; qi < 4; ++qi) {
                float mn = fmaxf(m[qi], mt[qi]);
                float a  = __builtin_amdgcn_exp2f(m[qi] - mn);
                m[qi] = mn;
                l_acc[qi] *= a;
#pragma unroll
                for (int mi = 0; mi < 4; ++mi) oacc[mi][qi] *= a;
            }
        }
        bf16x4 pb[4];
#pragma unroll
        for (int qi = 0; qi < 4; ++qi) {
            float e0 = __builtin_amdgcn_exp2f(st[qi][0] - m[qi]);
            float e1 = __builtin_amdgcn_exp2f(st[qi][1] - m[qi]);
            float e2 = __builtin_amdgcn_exp2f(st[qi][2] - m[qi]);
            float e3 = __builtin_amdgcn_exp2f(st[qi][3] - m[qi]);
            uint2 u = make_uint2(cvt_pk_bf16(e0, e1), cvt_pk_bf16(e2, e3));
            pb[qi] = __builtin_bit_cast(bf16x4, u);
        }

        // ---- PV + l accumulation (MFMA cluster) ----
        __builtin_amdgcn_s_setprio(1);
#pragma unroll
        for (int qi = 0; qi < 4; ++qi) {
            l_acc[qi] = mfma_16x16x16_bf16(vones, pb[qi], l_acc[qi]);
#pragma unroll
            for (int mi = 0; mi < 4; ++mi)
                oacc[mi][qi] = mfma_16x16x16_bf16(av[mi], pb[qi], oacc[mi][qi]);
        }
        __builtin_amdgcn_s_setprio(0);

        __syncthreads();
        if (tt < 63) {
#pragma unroll
            for (int qi = 0; qi < 4; ++qi) st[qi] = stn[qi];
        }
        // rotate buffers
        char* tk = kcur; kcur = knxt; knxt = kstg; kstg = tk;
        char* tv = vcur; vcur = vnxt; vnxt = vstg; vstg = tv;
    }

    // ---- cross-wave combine: publish (m, l) per q ----
    if (lane < 16) {
#pragma unroll
        for (int qi = 0; qi < 4; ++qi) {
            mlb[w][0][16 * qi + lane] = m[qi];
            mlb[w][1][16 * qi + lane] = l_acc[qi][0];
        }
    }
    __syncthreads();

    float sc[4], L[4];
#pragma unroll
    for (int qi = 0; qi < 4; ++qi) {
        int q = 16 * qi + c;
        float m0 = mlb[0][0][q], m1 = mlb[1][0][q], m2 = mlb[2][0][q], m3 = mlb[3][0][q];
        float M = fmaxf(fmaxf(m0, m1), fmaxf(m2, m3));
        L[qi] = mlb[0][1][q] * __builtin_amdgcn_exp2f(m0 - M) +
                mlb[1][1][q] * __builtin_amdgcn_exp2f(m1 - M) +
                mlb[2][1][q] * __builtin_amdgcn_exp2f(m2 - M) +
                mlb[3][1][q] * __builtin_amdgcn_exp2f(m3 - M);
        sc[qi] = __builtin_amdgcn_exp2f(m[qi] - M);
    }
    if (w == 0 && lane < 16) {
#pragma unroll
        for (int qi = 0; qi < 4; ++qi) Lq[16 * qi + lane] = L[qi];
    }

    // ---- serial 4-phase scaled add into buf[q][ch] ----
#pragma unroll
    for (int ph = 0; ph < 4; ++ph) {
        if (w == ph) {
#pragma unroll
            for (int mi = 0; mi < 4; ++mi)
#pragma unroll
                for (int qi = 0; qi < 4; ++qi)
#pragma unroll
                    for (int r = 0; r < 4; ++r) {
                        float v = oacc[mi][qi][r] * sc[qi];
                        float* p = &buf[16 * qi + c][16 * mi + 4 * g + r];
                        if (ph == 0) *p = v; else *p += v;
                    }
        }
        __syncthreads();
    }

    // ---- epilogue: wave w handles q rows q0+16w..+15; out = o @ Wo^T + bo + x ----
    int qw = q0 + 16 * w;
    float invL = 1.0f / Lq[16 * w + c];
    bf16x8 ao[2];
#pragma unroll
    for (int kk = 0; kk < 2; ++kk) {
        bf16x8 tr;
#pragma unroll
        for (int j = 0; j < 8; ++j) tr[j] = f2bf(buf[16 * w + c][32 * kk + 8 * g + j] * invL);
        ao[kk] = tr;
    }
#pragma unroll
    for (int n = 0; n < 4; ++n) {
        floatx4 a = {0.f, 0.f, 0.f, 0.f};
#pragma unroll
        for (int kk = 0; kk < 2; ++kk) {
            bf16x8 bw = ld_w_frag(Wo, n, kk, g, c);
            a = __builtin_amdgcn_mfma_f32_16x16x32_bf16(ao[kk], bw, a, 0, 0, 0);
        }
        float bov = bo[16 * n + c];
#pragma unroll
        for (int r = 0; r < 4; ++r) {
            int srow = qw + 4 * g + r;
            size_t idx = ((size_t)b * S_ + srow) * C_ + 16 * n + c;
            out[idx] = x[idx] + bov + a[r];
        }
    }
}

extern "C" void kernel_launch(void* const* d_in, const int* in_sizes, int n_in,
                              void* d_out, int out_size, void* d_ws, size_t ws_size,
                              hipStream_t stream) {
    const float* x  = (const float*)d_in[0];
    // d_in[1] = temb (unused by reference)
    const float* Wq = (const float*)d_in[2];
    const float* bq = (const float*)d_in[3];
    const float* Wk = (const float*)d_in[4];
    const float* bk = (const float*)d_in[5];
    const float* Wv = (const float*)d_in[6];
    const float* bv = (const float*)d_in[7];
    const float* Wo = (const float*)d_in[8];
    const float* bo = (const float*)d_in[9];
    float* out = (float*)d_out;

    char* ws = (char*)d_ws;
    float* partial = (float*)ws;                    // 512 floats
    float* stats   = (float*)(ws + 2048);           // 16 floats
    short* q  = (short*)(ws + 4096);                // [B][S][C] bf16 (4 MB)
    char*  kt = (char*)(q + (size_t)B_ * S_ * C_);  // [B][64 tiles][8192 B] swizzled K
    char*  vt = kt + (size_t)B_ * 64 * 8192;        // [B][64 tiles][8192 B] swizzled V^T

    stats1_kernel<<<256, 256, 0, stream>>>(x, partial);
    stats2_kernel<<<1, 512, 0, stream>>>(partial, stats);
    proj_kernel<<<B_ * (S_ / 64), 256, 0, stream>>>(x, Wq, bq, Wk, bk, Wv, bv, stats, q, kt, vt);
    flash_kernel<<<B_ * (S_ / 64), 256, 0, stream>>>(q, kt, vt, Wo, bo, x, out);
}

// Round 11
// 114.919 us; speedup vs baseline: 1.2855x; 1.2855x over previous
//
#include <hip/hip_runtime.h>
#include <hip/hip_bf16.h>
#include <math.h>

#define B_ 8
#define S_ 4096
#define C_ 64
#define EPSV 1e-5f

using floatx4 = __attribute__((ext_vector_type(4))) float;
using bf16x8  = __attribute__((ext_vector_type(8))) short;
using bf16x4  = __attribute__((ext_vector_type(4))) short;

typedef __attribute__((address_space(3))) unsigned int       as3_u32;
typedef __attribute__((address_space(1))) const unsigned int as1_u32;

__device__ __forceinline__ short f2bf(float f) {
    unsigned u = __builtin_bit_cast(unsigned, f);
    u = u + 0x7fffu + ((u >> 16) & 1u);   // RNE
    return (short)(u >> 16);
}

__device__ __forceinline__ unsigned cvt_pk_bf16(float lo, float hi) {
    unsigned r;
    asm volatile("v_cvt_pk_bf16_f32 %0, %1, %2" : "=v"(r) : "v"(lo), "v"(hi));
    return r;
}

// PV MFMA: 16x16x16 bf16 (K=16) — B-fragment layout (col=c, k=4g+j) matches
// the swapped-QK^T accumulator layout directly -> no cross-lane redistribution.
__device__ __forceinline__ floatx4 mfma_16x16x16_bf16(bf16x4 a, bf16x4 b, floatx4 c) {
#if __has_builtin(__builtin_amdgcn_mfma_f32_16x16x16bf16_1k)
    return __builtin_amdgcn_mfma_f32_16x16x16bf16_1k(a, b, c, 0, 0, 0);
#else
    asm("v_mfma_f32_16x16x16_bf16 %0, %1, %2, %0" : "+v"(c) : "v"(a), "v"(b));
    return c;
#endif
}

// B-fragment from a row-major fp32 64x64 weight matrix.
__device__ __forceinline__ bf16x8 ld_w_frag(const float* __restrict__ W, int n, int kk, int g, int c) {
    const float* p = W + (16 * n + c) * C_ + 32 * kk + 8 * g;
    bf16x8 r;
#pragma unroll
    for (int j = 0; j < 8; ++j) r[j] = f2bf(p[j]);
    return r;
}

// ---------------- kernel 1a: per-chunk partial sums ----------------
__global__ __launch_bounds__(256) void stats1_kernel(const float* __restrict__ x,
                                                     float* __restrict__ partial) {
    int b = blockIdx.x >> 5, chunk = blockIdx.x & 31;
    const float4* xb = (const float4*)x + (size_t)b * 65536 + chunk * 2048;
    float s = 0.f, ss = 0.f;
#pragma unroll
    for (int i = 0; i < 8; ++i) {
        float4 v = xb[threadIdx.x + i * 256];
        s  += v.x + v.y + v.z + v.w;
        ss += v.x * v.x + v.y * v.y + v.z * v.z + v.w * v.w;
    }
    for (int off = 32; off > 0; off >>= 1) {
        s  += __shfl_down(s, off);
        ss += __shfl_down(ss, off);
    }
    __shared__ float sm[4], ssm[4];
    int wid = threadIdx.x >> 6, lane = threadIdx.x & 63;
    if (lane == 0) { sm[wid] = s; ssm[wid] = ss; }
    __syncthreads();
    if (threadIdx.x == 0) {
        partial[blockIdx.x * 2]     = sm[0] + sm[1] + sm[2] + sm[3];
        partial[blockIdx.x * 2 + 1] = ssm[0] + ssm[1] + ssm[2] + ssm[3];
    }
}

// ---------------- kernel 1b: finalize mean / rsqrt(var) ----------------
__global__ __launch_bounds__(512) void stats2_kernel(const float* __restrict__ partial,
                                                     float* __restrict__ stats) {
    int w = threadIdx.x >> 6, lane = threadIdx.x & 63;  // wave w = batch w
    float s = 0.f, ss = 0.f;
    if (lane < 32) {
        s  = partial[(w * 32 + lane) * 2];
        ss = partial[(w * 32 + lane) * 2 + 1];
    }
    for (int off = 16; off > 0; off >>= 1) {
        s  += __shfl_down(s, off);
        ss += __shfl_down(ss, off);
    }
    if (lane == 0) {
        const float invN = 1.0f / (float)(S_ * C_);
        float mu  = s * invN;
        float var = ss * invN - mu * mu;
        stats[w * 2]     = mu;
        stats[w * 2 + 1] = rsqrtf(var + EPSV);
    }
}

// ---------------- kernel 2: normalize + Q/K/V^T projections ----------------
// K and V^T are written as per-64-kv TILE IMAGES (8192 B each), XOR-swizzled
// exactly as the flash kernel's LDS wants them (both-sides rule).
//   K tile:  [64 kv-rows][64 ch] bf16, byte = (r*128 + ch*2) ^ ((r&7)<<4)
//   V tile:  [64 ch-rows][64 kv] bf16, byte = (ch*128 + u*2) ^ ((ch&7)<<4)
__global__ __launch_bounds__(256) void proj_kernel(
    const float* __restrict__ x,
    const float* __restrict__ Wq, const float* __restrict__ bq,
    const float* __restrict__ Wk, const float* __restrict__ bk,
    const float* __restrict__ Wv, const float* __restrict__ bv,
    const float* __restrict__ stats,
    short* __restrict__ qo, char* __restrict__ kws, char* __restrict__ vws) {
    __shared__ char hbuf[64 * 128];  // [64 rows][64 bf16], XOR-swizzled

    int b  = blockIdx.x >> 6;
    int t_ = blockIdx.x & 63;        // 64-row tile index within batch
    int s0 = t_ * 64;
    float mu = stats[b * 2], rs = stats[b * 2 + 1];
    const float* xt = x + ((size_t)b * S_ + s0) * C_;
    int t = threadIdx.x;

#pragma unroll
    for (int i = 0; i < 4; ++i) {
        int fi  = t + 256 * i;       // float4 index within 64x64 tile
        int row = fi >> 4;
        int c4  = fi & 15;
        float4 v = *(const float4*)(xt + row * C_ + c4 * 4);
        unsigned lo = (unsigned)(unsigned short)f2bf((v.x - mu) * rs) |
                      ((unsigned)(unsigned short)f2bf((v.y - mu) * rs) << 16);
        unsigned hi = (unsigned)(unsigned short)f2bf((v.z - mu) * rs) |
                      ((unsigned)(unsigned short)f2bf((v.w - mu) * rs) << 16);
        int off = row * 128 + c4 * 8;
        off ^= (row & 7) << 4;
        *(uint2*)(hbuf + off) = make_uint2(lo, hi);
    }
    __syncthreads();

    int lane = t & 63, w = t >> 6;
    int g = lane >> 4, c = lane & 15;

    auto ld_h = [&](int row, int kcol) -> bf16x8 {
        int off = row * 128 + kcol * 2;
        off ^= (row & 7) << 4;
        return *(const bf16x8*)(hbuf + off);
    };

    size_t tilebase = ((size_t)b * 64 + t_) * 8192;

    // ---- Q and K: D = h @ W^T.  A = h rows 16w..16w+15 ----
    bf16x8 ha[2];
    ha[0] = ld_h(16 * w + c, 8 * g);
    ha[1] = ld_h(16 * w + c, 32 + 8 * g);

    const float QSC = 0.125f * 1.44269504088896340736f;  // C^-0.5 * log2(e)

#pragma unroll
    for (int n = 0; n < 4; ++n) {
        floatx4 aq = {0.f, 0.f, 0.f, 0.f}, ak = {0.f, 0.f, 0.f, 0.f};
#pragma unroll
        for (int kk = 0; kk < 2; ++kk) {
            bf16x8 wq = ld_w_frag(Wq, n, kk, g, c);
            bf16x8 wk = ld_w_frag(Wk, n, kk, g, c);
            aq = __builtin_amdgcn_mfma_f32_16x16x32_bf16(ha[kk], wq, aq, 0, 0, 0);
            ak = __builtin_amdgcn_mfma_f32_16x16x32_bf16(ha[kk], wk, ak, 0, 0, 0);
        }
        float bqv = bq[16 * n + c], bkv = bk[16 * n + c];
#pragma unroll
        for (int r = 0; r < 4; ++r) {
            int rr = 16 * w + 4 * g + r;          // kv row within tile
            qo[((size_t)b * S_ + s0 + rr) * C_ + 16 * n + c] = f2bf((aq[r] + bqv) * QSC);
            int koff = (rr * 128 + (16 * n + c) * 2) ^ ((rr & 7) << 4);
            *(short*)(kws + tilebase + koff) = f2bf(ak[r] + bkv);
        }
    }

    // ---- V^T = Wv @ h^T (direct transposed, swizzled tile image) ----
    bf16x8 wv[2];
    wv[0] = ld_w_frag(Wv, w, 0, g, c);
    wv[1] = ld_w_frag(Wv, w, 1, g, c);
    float bvr[4];
#pragma unroll
    for (int r = 0; r < 4; ++r) bvr[r] = bv[16 * w + 4 * g + r];

#pragma unroll
    for (int n = 0; n < 4; ++n) {
        floatx4 av = {0.f, 0.f, 0.f, 0.f};
#pragma unroll
        for (int kk = 0; kk < 2; ++kk) {
            bf16x8 hb = ld_h(16 * n + c, 32 * kk + 8 * g);
            av = __builtin_amdgcn_mfma_f32_16x16x32_bf16(wv[kk], hb, av, 0, 0, 0);
        }
#pragma unroll
        for (int r = 0; r < 4; ++r) {
            int rr = 16 * w + 4 * g + r;          // channel row
            int u  = 16 * n + c;                  // kv col within tile
            int voff = (rr * 128 + u * 2) ^ ((rr & 7) << 4);
            *(short*)(vws + tilebase + voff) = f2bf(av[r] + bvr[r]);
        }
    }
}

// ---------------- kernel 3: 8-wave flash attention + Wo + residual ----------------
// Block = 64 q rows, 8 waves (512 thr). Waves 0-3 process EVEN tiles, 4-7 ODD
// tiles (pair double-buffer); within a tile wave uses kv slice 16*(w&3).
// 2 blocks/CU x 8 waves = 16 waves/CU (R10 lesson: TLP beats in-wave ILP here).
// Epilogue combine buffers alias the 64KB tile LDS (dead after main loop).
__global__ __launch_bounds__(512) void flash_kernel(
    const short* __restrict__ qm, const char* __restrict__ kws, const char* __restrict__ vws,
    const float* __restrict__ Wo, const float* __restrict__ bo,
    const float* __restrict__ x, float* __restrict__ out) {
    __shared__ char lds[65536];   // [0,32K): 4 K-tiles; [32K,64K): 4 V-tiles
                                  // epilogue alias: buf 64x68 f32 @0, mlb @17408, Lq @21504

    int bid = blockIdx.x;
    int logical = (bid & 7) * 64 + (bid >> 3);  // XCD swizzle: batch b -> XCD b
    int b = logical >> 6;
    int q0 = (logical & 63) * 64;
    int t = threadIdx.x;
    int lane = t & 63, w = t >> 6;   // 8 waves
    int g = lane >> 4, c = lane & 15;
    int par = w >> 2;                 // tile parity this wave owns
    int s   = w & 3;                  // kv slice (rows 16s..16s+15) within tile

    const char* kbase = kws + (size_t)b * 64 * 8192;
    const char* vbase = vws + (size_t)b * 64 * 8192;
    const short* qp = qm + (size_t)b * S_ * C_;

    // Q^T B-fragments for ALL 64 q rows (4 subtiles), held in regs.
    bf16x8 bqf[4][2];
#pragma unroll
    for (int qi = 0; qi < 4; ++qi) {
        bqf[qi][0] = *(const bf16x8*)(qp + (q0 + 16 * qi + c) * C_ + 8 * g);
        bqf[qi][1] = *(const bf16x8*)(qp + (q0 + 16 * qi + c) * C_ + 32 + 8 * g);
    }

    floatx4 oacc[4][4];                // [mi(ch)][qi]
#pragma unroll
    for (int mi = 0; mi < 4; ++mi)
#pragma unroll
        for (int qi = 0; qi < 4; ++qi) oacc[mi][qi] = (floatx4){0.f, 0.f, 0.f, 0.f};
    float m[4], l[4];
#pragma unroll
    for (int qi = 0; qi < 4; ++qi) { m[qi] = -__builtin_inff(); l[qi] = 0.f; }

    const int xmask = (c & 7) << 4;   // per-lane row-swizzle mask (bits 4-6)
    const int krd = s * 2048 + c * 128;                    // K slice base
    const int vrd = c * 128 + ((32 * s + 8 * g) ^ xmask);  // V slice col base

    // stage tiles (tt0, tt0+1) into phase ph; this wave covers tile tt0+par,
    // bytes [2048*s, 2048*s+2048) of both K and V images.
    auto STAGE = [&](int ph, int tt0) {
        int tt = tt0 + par;
        const char* gk = kbase + (size_t)tt * 8192 + s * 2048 + lane * 16;
        const char* gv = vbase + (size_t)tt * 8192 + s * 2048 + lane * 16;
        char* lk = lds +         (ph * 2 + par) * 8192 + s * 2048 + lane * 16;
        char* lv = lds + 32768 + (ph * 2 + par) * 8192 + s * 2048 + lane * 16;
        __builtin_amdgcn_global_load_lds((as1_u32*)gk,          (as3_u32*)lk,          16, 0, 0);
        __builtin_amdgcn_global_load_lds((as1_u32*)(gk + 1024), (as3_u32*)(lk + 1024), 16, 0, 0);
        __builtin_amdgcn_global_load_lds((as1_u32*)gv,          (as3_u32*)lv,          16, 0, 0);
        __builtin_amdgcn_global_load_lds((as1_u32*)(gv + 1024), (as3_u32*)(lv + 1024), 16, 0, 0);
    };

    auto COMPUTE = [&](int ph) {
        const char* kbuf = lds +         (ph * 2 + par) * 8192;
        const char* vbuf = lds + 32768 + (ph * 2 + par) * 8192;
        // K slice (rows 16s..16s+15): 2 x ds_read_b128
        bf16x8 ak0 = *(const bf16x8*)(kbuf + krd + ((16 * g) ^ xmask));
        bf16x8 ak1 = *(const bf16x8*)(kbuf + krd + ((64 + 16 * g) ^ xmask));
        // ---- S^T slice (16 kv x 64 q) ----
        floatx4 st[4];
        __builtin_amdgcn_s_setprio(1);
#pragma unroll
        for (int qi = 0; qi < 4; ++qi) {
            st[qi] = (floatx4){0.f, 0.f, 0.f, 0.f};
            st[qi] = __builtin_amdgcn_mfma_f32_16x16x32_bf16(ak0, bqf[qi][0], st[qi], 0, 0, 0);
            st[qi] = __builtin_amdgcn_mfma_f32_16x16x32_bf16(ak1, bqf[qi][1], st[qi], 0, 0, 0);
        }
        __builtin_amdgcn_s_setprio(0);
        // V slice (kv cols 16s..16s+15), independent of softmax
        bf16x4 av[4];
#pragma unroll
        for (int mi = 0; mi < 4; ++mi)
            av[mi] = *(const bf16x4*)(vbuf + mi * 2048 + vrd);
        // ---- online softmax (q = 16qi + c; log2-domain); single rescale branch ----
        float mt[4], need = -1e30f;
#pragma unroll
        for (int qi = 0; qi < 4; ++qi) {
            float v = fmaxf(fmaxf(st[qi][0], st[qi][1]), fmaxf(st[qi][2], st[qi][3]));
            v = fmaxf(v, __shfl_xor(v, 16));
            v = fmaxf(v, __shfl_xor(v, 32));
            mt[qi] = v;
            need = fmaxf(need, v - m[qi]);
        }
        if (!__all(need <= 8.0f)) {
#pragma unroll
            for (int qi = 0; qi < 4; ++qi) {
                float mn = fmaxf(m[qi], mt[qi]);
                float a  = __builtin_amdgcn_exp2f(m[qi] - mn);
                m[qi] = mn;
                l[qi] *= a;
#pragma unroll
                for (int mi = 0; mi < 4; ++mi) oacc[mi][qi] *= a;
            }
        }
        bf16x4 pb[4];
#pragma unroll
        for (int qi = 0; qi < 4; ++qi) {
            float e0 = __builtin_amdgcn_exp2f(st[qi][0] - m[qi]);
            float e1 = __builtin_amdgcn_exp2f(st[qi][1] - m[qi]);
            float e2 = __builtin_amdgcn_exp2f(st[qi][2] - m[qi]);
            float e3 = __builtin_amdgcn_exp2f(st[qi][3] - m[qi]);
            l[qi] += (e0 + e1) + (e2 + e3);
            uint2 u = make_uint2(cvt_pk_bf16(e0, e1), cvt_pk_bf16(e2, e3));
            pb[qi] = __builtin_bit_cast(bf16x4, u);
        }
        // ---- O^T partial += V^T @ P^T (16 independent MFMA16) ----
        __builtin_amdgcn_s_setprio(1);
#pragma unroll
        for (int qi = 0; qi < 4; ++qi)
#pragma unroll
            for (int mi = 0; mi < 4; ++mi)
                oacc[mi][qi] = mfma_16x16x16_bf16(av[mi], pb[qi], oacc[mi][qi]);
        __builtin_amdgcn_s_setprio(0);
    };

    STAGE(0, 0);
    __syncthreads();
    for (int r = 0; r < 32; ++r) {
        if (r < 31) STAGE((r + 1) & 1, 2 * (r + 1));
        COMPUTE(r & 1);
        __syncthreads();
    }

    // ---- cross-wave combine (aliased LDS): publish (m, l) per q ----
    float* mlb = (float*)(lds + 17408);   // [8 waves][2][64 q]
    float* Lq  = (float*)(lds + 21504);   // [64]
#pragma unroll
    for (int qi = 0; qi < 4; ++qi) {
        l[qi] += __shfl_xor(l[qi], 16);
        l[qi] += __shfl_xor(l[qi], 32);
    }
    if (lane < 16) {
#pragma unroll
        for (int qi = 0; qi < 4; ++qi) {
            mlb[(w * 2 + 0) * 64 + 16 * qi + lane] = m[qi];
            mlb[(w * 2 + 1) * 64 + 16 * qi + lane] = l[qi];
        }
    }
    __syncthreads();

    float sc[4], Lv[4];
#pragma unroll
    for (int qi = 0; qi < 4; ++qi) {
        int q = 16 * qi + c;
        float M = -__builtin_inff();
#pragma unroll
        for (int ww = 0; ww < 8; ++ww) M = fmaxf(M, mlb[(ww * 2) * 64 + q]);
        float L = 0.f;
#pragma unroll
        for (int ww = 0; ww < 8; ++ww)
            L += mlb[(ww * 2 + 1) * 64 + q] * __builtin_amdgcn_exp2f(mlb[(ww * 2) * 64 + q] - M);
        Lv[qi] = L;
        sc[qi] = __builtin_amdgcn_exp2f(m[qi] - M);
    }
    if (w == 0 && lane < 16) {
#pragma unroll
        for (int qi = 0; qi < 4; ++qi) Lq[16 * qi + lane] = Lv[qi];
    }

    // ---- serial 8-phase scaled add into buf[q][ch] (aliased at lds+0) ----
    float (*buf)[68] = (float (*)[68])lds;
#pragma unroll
    for (int ph = 0; ph < 8; ++ph) {
        if (w == ph) {
#pragma unroll
            for (int mi = 0; mi < 4; ++mi)
#pragma unroll
                for (int qi = 0; qi < 4; ++qi)
#pragma unroll
                    for (int r = 0; r < 4; ++r) {
                        float v = oacc[mi][qi][r] * sc[qi];
                        float* p = &buf[16 * qi + c][16 * mi + 4 * g + r];
                        if (ph == 0) *p = v; else *p += v;
                    }
        }
        __syncthreads();
    }

    // ---- epilogue: wave w -> q rows 16s..16s+15, out cols n = 2*par + {0,1} ----
    int qrow = 16 * s + c;
    float invL = 1.0f / Lq[qrow];
    bf16x8 ao[2];
#pragma unroll
    for (int kk = 0; kk < 2; ++kk) {
        bf16x8 tr;
#pragma unroll
        for (int j = 0; j < 8; ++j) tr[j] = f2bf(buf[qrow][32 * kk + 8 * g + j] * invL);
        ao[kk] = tr;
    }
#pragma unroll
    for (int nn = 0; nn < 2; ++nn) {
        int n = 2 * par + nn;
        floatx4 a = {0.f, 0.f, 0.f, 0.f};
#pragma unroll
        for (int kk = 0; kk < 2; ++kk) {
            bf16x8 bw = ld_w_frag(Wo, n, kk, g, c);
            a = __builtin_amdgcn_mfma_f32_16x16x32_bf16(ao[kk], bw, a, 0, 0, 0);
        }
        float bov = bo[16 * n + c];
#pragma unroll
        for (int r = 0; r < 4; ++r) {
            int srow = q0 + 16 * s + 4 * g + r;
            size_t idx = ((size_t)b * S_ + srow) * C_ + 16 * n + c;
            out[idx] = x[idx] + bov + a[r];
        }
    }
}

extern "C" void kernel_launch(void* const* d_in, const int* in_sizes, int n_in,
                              void* d_out, int out_size, void* d_ws, size_t ws_size,
                              hipStream_t stream) {
    const float* x  = (const float*)d_in[0];
    // d_in[1] = temb (unused by reference)
    const float* Wq = (const float*)d_in[2];
    const float* bq = (const float*)d_in[3];
    const float* Wk = (const float*)d_in[4];
    const float* bk = (const float*)d_in[5];
    const float* Wv = (const float*)d_in[6];
    const float* bv = (const float*)d_in[7];
    const float* Wo = (const float*)d_in[8];
    const float* bo = (const float*)d_in[9];
    float* out = (float*)d_out;

    char* ws = (char*)d_ws;
    float* partial = (float*)ws;                    // 512 floats
    float* stats   = (float*)(ws + 2048);           // 16 floats
    short* q  = (short*)(ws + 4096);                // [B][S][C] bf16 (4 MB)
    char*  kt = (char*)(q + (size_t)B_ * S_ * C_);  // [B][64 tiles][8192 B] swizzled K
    char*  vt = kt + (size_t)B_ * 64 * 8192;        // [B][64 tiles][8192 B] swizzled V^T

    stats1_kernel<<<256, 256, 0, stream>>>(x, partial);
    stats2_kernel<<<1, 512, 0, stream>>>(partial, stats);
    proj_kernel<<<B_ * (S_ / 64), 256, 0, stream>>>(x, Wq, bq, Wk, bk, Wv, bv, stats, q, kt, vt);
    flash_kernel<<<B_ * (S_ / 64), 512, 0, stream>>>(q, kt, vt, Wo, bo, x, out);
}

// Round 12
// 105.409 us; speedup vs baseline: 1.4015x; 1.0902x over previous
//
#include <hip/hip_runtime.h>
#include <hip/hip_bf16.h>
#include <math.h>

#define B_ 8
#define S_ 4096
#define C_ 64
#define EPSV 1e-5f

using floatx4 = __attribute__((ext_vector_type(4))) float;
using bf16x8  = __attribute__((ext_vector_type(8))) short;
using bf16x4  = __attribute__((ext_vector_type(4))) short;

typedef __attribute__((address_space(3))) unsigned int       as3_u32;
typedef __attribute__((address_space(1))) const unsigned int as1_u32;

__device__ __forceinline__ short f2bf(float f) {
    unsigned u = __builtin_bit_cast(unsigned, f);
    u = u + 0x7fffu + ((u >> 16) & 1u);   // RNE
    return (short)(u >> 16);
}

__device__ __forceinline__ float bf2f(short s) {
    return __builtin_bit_cast(float, ((unsigned)(unsigned short)s) << 16);
}

__device__ __forceinline__ unsigned cvt_pk_bf16(float lo, float hi) {
    unsigned r;
    asm volatile("v_cvt_pk_bf16_f32 %0, %1, %2" : "=v"(r) : "v"(lo), "v"(hi));
    return r;
}

// PV MFMA: 16x16x16 bf16 (K=16) — B-fragment layout (col=c, k=4g+j) matches
// the swapped-QK^T accumulator layout directly -> no cross-lane redistribution.
__device__ __forceinline__ floatx4 mfma_16x16x16_bf16(bf16x4 a, bf16x4 b, floatx4 c) {
#if __has_builtin(__builtin_amdgcn_mfma_f32_16x16x16bf16_1k)
    return __builtin_amdgcn_mfma_f32_16x16x16bf16_1k(a, b, c, 0, 0, 0);
#else
    asm("v_mfma_f32_16x16x16_bf16 %0, %1, %2, %0" : "+v"(c) : "v"(a), "v"(b));
    return c;
#endif
}

// B-fragment from a row-major fp32 64x64 weight matrix.
__device__ __forceinline__ bf16x8 ld_w_frag(const float* __restrict__ W, int n, int kk, int g, int c) {
    const float* p = W + (16 * n + c) * C_ + 32 * kk + 8 * g;
    bf16x8 r;
#pragma unroll
    for (int j = 0; j < 8; ++j) r[j] = f2bf(p[j]);
    return r;
}

// ---------------- kernel 1a: per-chunk partial sums ----------------
__global__ __launch_bounds__(256) void stats1_kernel(const float* __restrict__ x,
                                                     float* __restrict__ partial) {
    int b = blockIdx.x >> 5, chunk = blockIdx.x & 31;
    const float4* xb = (const float4*)x + (size_t)b * 65536 + chunk * 2048;
    float s = 0.f, ss = 0.f;
#pragma unroll
    for (int i = 0; i < 8; ++i) {
        float4 v = xb[threadIdx.x + i * 256];
        s  += v.x + v.y + v.z + v.w;
        ss += v.x * v.x + v.y * v.y + v.z * v.z + v.w * v.w;
    }
    for (int off = 32; off > 0; off >>= 1) {
        s  += __shfl_down(s, off);
        ss += __shfl_down(ss, off);
    }
    __shared__ float sm[4], ssm[4];
    int wid = threadIdx.x >> 6, lane = threadIdx.x & 63;
    if (lane == 0) { sm[wid] = s; ssm[wid] = ss; }
    __syncthreads();
    if (threadIdx.x == 0) {
        partial[blockIdx.x * 2]     = sm[0] + sm[1] + sm[2] + sm[3];
        partial[blockIdx.x * 2 + 1] = ssm[0] + ssm[1] + ssm[2] + ssm[3];
    }
}

// ---------------- kernel 1b: finalize mean / rsqrt(var) ----------------
__global__ __launch_bounds__(512) void stats2_kernel(const float* __restrict__ partial,
                                                     float* __restrict__ stats) {
    int w = threadIdx.x >> 6, lane = threadIdx.x & 63;  // wave w = batch w
    float s = 0.f, ss = 0.f;
    if (lane < 32) {
        s  = partial[(w * 32 + lane) * 2];
        ss = partial[(w * 32 + lane) * 2 + 1];
    }
    for (int off = 16; off > 0; off >>= 1) {
        s  += __shfl_down(s, off);
        ss += __shfl_down(ss, off);
    }
    if (lane == 0) {
        const float invN = 1.0f / (float)(S_ * C_);
        float mu  = s * invN;
        float var = ss * invN - mu * mu;
        stats[w * 2]     = mu;
        stats[w * 2 + 1] = rsqrtf(var + EPSV);
    }
}

// ---------------- kernel 2: normalize + Q/K/V^T projections ----------------
// K and V^T are written as per-64-kv TILE IMAGES (8192 B each), XOR-swizzled
// exactly as the flash kernel's LDS wants them (both-sides rule).
//   K tile:  [64 kv-rows][64 ch] bf16, byte = (r*128 + ch*2) ^ ((r&7)<<4)
//   V tile:  [64 ch-rows][64 kv] bf16, byte = (ch*128 + u*2) ^ ((ch&7)<<4)
__global__ __launch_bounds__(256) void proj_kernel(
    const float* __restrict__ x,
    const float* __restrict__ Wq, const float* __restrict__ bq,
    const float* __restrict__ Wk, const float* __restrict__ bk,
    const float* __restrict__ Wv, const float* __restrict__ bv,
    const float* __restrict__ stats,
    short* __restrict__ qo, char* __restrict__ kws, char* __restrict__ vws) {
    __shared__ char hbuf[64 * 128];  // [64 rows][64 bf16], XOR-swizzled

    int b  = blockIdx.x >> 6;
    int t_ = blockIdx.x & 63;        // 64-row tile index within batch
    int s0 = t_ * 64;
    float mu = stats[b * 2], rs = stats[b * 2 + 1];
    const float* xt = x + ((size_t)b * S_ + s0) * C_;
    int t = threadIdx.x;

#pragma unroll
    for (int i = 0; i < 4; ++i) {
        int fi  = t + 256 * i;       // float4 index within 64x64 tile
        int row = fi >> 4;
        int c4  = fi & 15;
        float4 v = *(const float4*)(xt + row * C_ + c4 * 4);
        unsigned lo = (unsigned)(unsigned short)f2bf((v.x - mu) * rs) |
                      ((unsigned)(unsigned short)f2bf((v.y - mu) * rs) << 16);
        unsigned hi = (unsigned)(unsigned short)f2bf((v.z - mu) * rs) |
                      ((unsigned)(unsigned short)f2bf((v.w - mu) * rs) << 16);
        int off = row * 128 + c4 * 8;
        off ^= (row & 7) << 4;
        *(uint2*)(hbuf + off) = make_uint2(lo, hi);
    }
    __syncthreads();

    int lane = t & 63, w = t >> 6;
    int g = lane >> 4, c = lane & 15;

    auto ld_h = [&](int row, int kcol) -> bf16x8 {
        int off = row * 128 + kcol * 2;
        off ^= (row & 7) << 4;
        return *(const bf16x8*)(hbuf + off);
    };

    size_t tilebase = ((size_t)b * 64 + t_) * 8192;

    // ---- Q and K: D = h @ W^T.  A = h rows 16w..16w+15 ----
    bf16x8 ha[2];
    ha[0] = ld_h(16 * w + c, 8 * g);
    ha[1] = ld_h(16 * w + c, 32 + 8 * g);

    const float QSC = 0.125f * 1.44269504088896340736f;  // C^-0.5 * log2(e)

#pragma unroll
    for (int n = 0; n < 4; ++n) {
        floatx4 aq = {0.f, 0.f, 0.f, 0.f}, ak = {0.f, 0.f, 0.f, 0.f};
#pragma unroll
        for (int kk = 0; kk < 2; ++kk) {
            bf16x8 wq = ld_w_frag(Wq, n, kk, g, c);
            bf16x8 wk = ld_w_frag(Wk, n, kk, g, c);
            aq = __builtin_amdgcn_mfma_f32_16x16x32_bf16(ha[kk], wq, aq, 0, 0, 0);
            ak = __builtin_amdgcn_mfma_f32_16x16x32_bf16(ha[kk], wk, ak, 0, 0, 0);
        }
        float bqv = bq[16 * n + c], bkv = bk[16 * n + c];
#pragma unroll
        for (int r = 0; r < 4; ++r) {
            int rr = 16 * w + 4 * g + r;          // kv row within tile
            qo[((size_t)b * S_ + s0 + rr) * C_ + 16 * n + c] = f2bf((aq[r] + bqv) * QSC);
            int koff = (rr * 128 + (16 * n + c) * 2) ^ ((rr & 7) << 4);
            *(short*)(kws + tilebase + koff) = f2bf(ak[r] + bkv);
        }
    }

    // ---- V^T = Wv @ h^T (direct transposed, swizzled tile image) ----
    bf16x8 wv[2];
    wv[0] = ld_w_frag(Wv, w, 0, g, c);
    wv[1] = ld_w_frag(Wv, w, 1, g, c);
    float bvr[4];
#pragma unroll
    for (int r = 0; r < 4; ++r) bvr[r] = bv[16 * w + 4 * g + r];

#pragma unroll
    for (int n = 0; n < 4; ++n) {
        floatx4 av = {0.f, 0.f, 0.f, 0.f};
#pragma unroll
        for (int kk = 0; kk < 2; ++kk) {
            bf16x8 hb = ld_h(16 * n + c, 32 * kk + 8 * g);
            av = __builtin_amdgcn_mfma_f32_16x16x32_bf16(wv[kk], hb, av, 0, 0, 0);
        }
#pragma unroll
        for (int r = 0; r < 4; ++r) {
            int rr = 16 * w + 4 * g + r;          // channel row
            int u  = 16 * n + c;                  // kv col within tile
            int voff = (rr * 128 + u * 2) ^ ((rr & 7) << 4);
            *(short*)(vws + tilebase + voff) = f2bf(av[r] + bvr[r]);
        }
    }
}

// ---------------- kernel 3: KV-split wave-sliced flash attention ----------------
// Grid 1024: block = (batch, 64-q-tile, kv-half). 4 waves, wave w slices kv
// rows 16w..16w+15 of each staged tile; 32 tiles per block. LDS 32KB (2-buf)
// -> 4 blocks/CU = 16 waves/CU of loosely-coupled 4-wave groups (R11 lesson:
// wide barrier coupling hurts; more independent blocks is the overlap lever).
// Output: unnormalized bf16 partial O + per-q (M,L) to workspace.
__global__ __launch_bounds__(256) void flash_kernel(
    const short* __restrict__ qm, const char* __restrict__ kws, const char* __restrict__ vws,
    short* __restrict__ Opart, float2* __restrict__ mlpart) {
    __shared__ char lds[32768];   // [0,16K): K dbuf; [16K,32K): V dbuf
                                  // epilogue alias: buf 64x68 f32 @0, mlb @18432

    int bid = blockIdx.x;
    int logical = (bid & 7) * 128 + (bid >> 3);  // XCD swizzle: batch b -> XCD b
    int b = logical >> 7;
    int rest = logical & 127;
    int q0 = (rest >> 1) * 64;
    int half = rest & 1;
    int t = threadIdx.x;
    int lane = t & 63, w = t >> 6;
    int g = lane >> 4, c = lane & 15;

    const char* kbase = kws + (size_t)b * 64 * 8192;
    const char* vbase = vws + (size_t)b * 64 * 8192;
    const short* qp = qm + (size_t)b * S_ * C_;

    // Q^T B-fragments for ALL 64 q rows (4 subtiles), held in regs.
    bf16x8 bqf[4][2];
#pragma unroll
    for (int qi = 0; qi < 4; ++qi) {
        bqf[qi][0] = *(const bf16x8*)(qp + (q0 + 16 * qi + c) * C_ + 8 * g);
        bqf[qi][1] = *(const bf16x8*)(qp + (q0 + 16 * qi + c) * C_ + 32 + 8 * g);
    }

    floatx4 oacc[4][4];                // [mi(ch)][qi]
#pragma unroll
    for (int mi = 0; mi < 4; ++mi)
#pragma unroll
        for (int qi = 0; qi < 4; ++qi) oacc[mi][qi] = (floatx4){0.f, 0.f, 0.f, 0.f};
    float m[4], l[4];
#pragma unroll
    for (int qi = 0; qi < 4; ++qi) { m[qi] = -__builtin_inff(); l[qi] = 0.f; }

    const int xmask = (c & 7) << 4;   // per-lane row-swizzle mask (bits 4-6)
    const int krd = w * 2048 + c * 128;                    // K slice base
    const int vrd = c * 128 + ((32 * w + 8 * g) ^ xmask);  // V slice col base

    auto STAGE = [&](int bi, int tt) {
        const char* gk = kbase + (size_t)tt * 8192 + w * 2048 + lane * 16;
        const char* gv = vbase + (size_t)tt * 8192 + w * 2048 + lane * 16;
        char* lk = lds +         bi * 8192 + w * 2048 + lane * 16;
        char* lv = lds + 16384 + bi * 8192 + w * 2048 + lane * 16;
        __builtin_amdgcn_global_load_lds((as1_u32*)gk,          (as3_u32*)lk,          16, 0, 0);
        __builtin_amdgcn_global_load_lds((as1_u32*)(gk + 1024), (as3_u32*)(lk + 1024), 16, 0, 0);
        __builtin_amdgcn_global_load_lds((as1_u32*)gv,          (as3_u32*)lv,          16, 0, 0);
        __builtin_amdgcn_global_load_lds((as1_u32*)(gv + 1024), (as3_u32*)(lv + 1024), 16, 0, 0);
    };

    auto COMPUTE = [&](int bi) {
        const char* kbuf = lds +         bi * 8192;
        const char* vbuf = lds + 16384 + bi * 8192;
        // K slice (rows 16w..16w+15): 2 x ds_read_b128
        bf16x8 ak0 = *(const bf16x8*)(kbuf + krd + ((16 * g) ^ xmask));
        bf16x8 ak1 = *(const bf16x8*)(kbuf + krd + ((64 + 16 * g) ^ xmask));
        // ---- S^T slice (16 kv x 64 q) ----
        floatx4 st[4];
        __builtin_amdgcn_s_setprio(1);
#pragma unroll
        for (int qi = 0; qi < 4; ++qi) {
            st[qi] = (floatx4){0.f, 0.f, 0.f, 0.f};
            st[qi] = __builtin_amdgcn_mfma_f32_16x16x32_bf16(ak0, bqf[qi][0], st[qi], 0, 0, 0);
            st[qi] = __builtin_amdgcn_mfma_f32_16x16x32_bf16(ak1, bqf[qi][1], st[qi], 0, 0, 0);
        }
        __builtin_amdgcn_s_setprio(0);
        // V slice (kv cols 16w..16w+15), independent of softmax
        bf16x4 av[4];
#pragma unroll
        for (int mi = 0; mi < 4; ++mi)
            av[mi] = *(const bf16x4*)(vbuf + mi * 2048 + vrd);
        // ---- online softmax (q = 16qi + c; log2-domain); single rescale branch ----
        float mt[4], need = -1e30f;
#pragma unroll
        for (int qi = 0; qi < 4; ++qi) {
            float v = fmaxf(fmaxf(st[qi][0], st[qi][1]), fmaxf(st[qi][2], st[qi][3]));
            v = fmaxf(v, __shfl_xor(v, 16));
            v = fmaxf(v, __shfl_xor(v, 32));
            mt[qi] = v;
            need = fmaxf(need, v - m[qi]);
        }
        if (!__all(need <= 8.0f)) {
#pragma unroll
            for (int qi = 0; qi < 4; ++qi) {
                float mn = fmaxf(m[qi], mt[qi]);
                float a  = __builtin_amdgcn_exp2f(m[qi] - mn);
                m[qi] = mn;
                l[qi] *= a;
#pragma unroll
                for (int mi = 0; mi < 4; ++mi) oacc[mi][qi] *= a;
            }
        }
        bf16x4 pb[4];
#pragma unroll
        for (int qi = 0; qi < 4; ++qi) {
            float e0 = __builtin_amdgcn_exp2f(st[qi][0] - m[qi]);
            float e1 = __builtin_amdgcn_exp2f(st[qi][1] - m[qi]);
            float e2 = __builtin_amdgcn_exp2f(st[qi][2] - m[qi]);
            float e3 = __builtin_amdgcn_exp2f(st[qi][3] - m[qi]);
            l[qi] += (e0 + e1) + (e2 + e3);
            uint2 u = make_uint2(cvt_pk_bf16(e0, e1), cvt_pk_bf16(e2, e3));
            pb[qi] = __builtin_bit_cast(bf16x4, u);
        }
        // ---- O^T partial += V^T @ P^T (16 independent MFMA16) ----
        __builtin_amdgcn_s_setprio(1);
#pragma unroll
        for (int qi = 0; qi < 4; ++qi)
#pragma unroll
            for (int mi = 0; mi < 4; ++mi)
                oacc[mi][qi] = mfma_16x16x16_bf16(av[mi], pb[qi], oacc[mi][qi]);
        __builtin_amdgcn_s_setprio(0);
    };

    const int base = half * 32;
    STAGE(0, base);
    __syncthreads();
    for (int r = 0; r < 32; r += 2) {
        STAGE(1, base + r + 1);
        COMPUTE(0);
        __syncthreads();
        if (r + 2 < 32) STAGE(0, base + r + 2);
        COMPUTE(1);
        __syncthreads();
    }

    // ---- cross-wave combine (aliased LDS): publish (m, l) per q ----
    float* mlb = (float*)(lds + 18432);   // [4 waves][2][64 q]
#pragma unroll
    for (int qi = 0; qi < 4; ++qi) {
        l[qi] += __shfl_xor(l[qi], 16);
        l[qi] += __shfl_xor(l[qi], 32);
    }
    if (lane < 16) {
#pragma unroll
        for (int qi = 0; qi < 4; ++qi) {
            mlb[(w * 2 + 0) * 64 + 16 * qi + lane] = m[qi];
            mlb[(w * 2 + 1) * 64 + 16 * qi + lane] = l[qi];
        }
    }
    __syncthreads();

    float sc[4], Lv[4], Mv[4];
#pragma unroll
    for (int qi = 0; qi < 4; ++qi) {
        int q = 16 * qi + c;
        float m0 = mlb[0 * 64 + q], m1 = mlb[2 * 64 + q];
        float m2 = mlb[4 * 64 + q], m3 = mlb[6 * 64 + q];
        float M = fmaxf(fmaxf(m0, m1), fmaxf(m2, m3));
        Lv[qi] = mlb[1 * 64 + q] * __builtin_amdgcn_exp2f(m0 - M) +
                 mlb[3 * 64 + q] * __builtin_amdgcn_exp2f(m1 - M) +
                 mlb[5 * 64 + q] * __builtin_amdgcn_exp2f(m2 - M) +
                 mlb[7 * 64 + q] * __builtin_amdgcn_exp2f(m3 - M);
        Mv[qi] = M;
        sc[qi] = __builtin_amdgcn_exp2f(m[qi] - M);
    }
    size_t prow = (size_t)(half * 8 + b) * S_ + q0;
    if (w == 0 && lane < 16) {
#pragma unroll
        for (int qi = 0; qi < 4; ++qi)
            mlpart[prow + 16 * qi + lane] = make_float2(Mv[qi], Lv[qi]);
    }

    // ---- serial 4-phase scaled add into buf[q][ch] (aliased at lds+0) ----
    float (*buf)[68] = (float (*)[68])lds;
#pragma unroll
    for (int ph = 0; ph < 4; ++ph) {
        if (w == ph) {
#pragma unroll
            for (int mi = 0; mi < 4; ++mi)
#pragma unroll
                for (int qi = 0; qi < 4; ++qi)
#pragma unroll
                    for (int r = 0; r < 4; ++r) {
                        float v = oacc[mi][qi][r] * sc[qi];
                        float* p = &buf[16 * qi + c][16 * mi + 4 * g + r];
                        if (ph == 0) *p = v; else *p += v;
                    }
        }
        __syncthreads();
    }

    // ---- write unnormalized bf16 partial tile ----
    short* op = Opart + prow * C_;
#pragma unroll
    for (int i = 0; i < 16; ++i) {
        int idx = t + 256 * i;
        int q = idx >> 6, ch = idx & 63;
        op[q * 64 + ch] = f2bf(buf[q][ch]);
    }
}

// ---------------- kernel 4: 2-way LSE combine + Wo + residual ----------------
__global__ __launch_bounds__(256) void combine_kernel(
    const short* __restrict__ Opart, const float2* __restrict__ mlpart,
    const float* __restrict__ Wo, const float* __restrict__ bo,
    const float* __restrict__ x, float* __restrict__ out) {
    __shared__ char obuf[8192];   // [64 q][64 ch] bf16, XOR-swizzled

    int bid = blockIdx.x;
    int logical = (bid & 7) * 64 + (bid >> 3);  // XCD swizzle: batch b -> XCD b
    int b = logical >> 6;
    int q0 = (logical & 63) * 64;
    int t = threadIdx.x;
    int lane = t & 63, w = t >> 6;
    int g = lane >> 4, c = lane & 15;

    const short*  P0  = Opart  + ((size_t)b * S_ + q0) * C_;
    const short*  P1  = Opart  + ((size_t)(8 + b) * S_ + q0) * C_;
    const float2* ml0 = mlpart + (size_t)b * S_ + q0;
    const float2* ml1 = mlpart + (size_t)(8 + b) * S_ + q0;

#pragma unroll
    for (int i = 0; i < 16; ++i) {
        int idx = t + 256 * i;
        int q = idx >> 6, ch = idx & 63;
        float2 a0 = ml0[q], a1 = ml1[q];
        float M  = fmaxf(a0.x, a1.x);
        float s0 = __builtin_amdgcn_exp2f(a0.x - M);
        float s1 = __builtin_amdgcn_exp2f(a1.x - M);
        float L  = a0.y * s0 + a1.y * s1;
        float o  = (bf2f(P0[q * 64 + ch]) * s0 + bf2f(P1[q * 64 + ch]) * s1) / L;
        int off = (q * 128 + ch * 2) ^ ((q & 7) << 4);
        *(short*)(obuf + off) = f2bf(o);
    }
    __syncthreads();

    // wave w handles q rows q0+16w..+15; out = o @ Wo^T + bo + x
    bf16x8 ao[2];
    {
        int row = 16 * w + c;
        int off0 = (row * 128 + (8 * g) * 2)      ^ ((row & 7) << 4);
        int off1 = (row * 128 + (32 + 8 * g) * 2) ^ ((row & 7) << 4);
        ao[0] = *(const bf16x8*)(obuf + off0);
        ao[1] = *(const bf16x8*)(obuf + off1);
    }
#pragma unroll
    for (int n = 0; n < 4; ++n) {
        floatx4 a = {0.f, 0.f, 0.f, 0.f};
#pragma unroll
        for (int kk = 0; kk < 2; ++kk) {
            bf16x8 bw = ld_w_frag(Wo, n, kk, g, c);
            a = __builtin_amdgcn_mfma_f32_16x16x32_bf16(ao[kk], bw, a, 0, 0, 0);
        }
        float bov = bo[16 * n + c];
#pragma unroll
        for (int r = 0; r < 4; ++r) {
            int srow = q0 + 16 * w + 4 * g + r;
            size_t idx = ((size_t)b * S_ + srow) * C_ + 16 * n + c;
            out[idx] = x[idx] + bov + a[r];
        }
    }
}

extern "C" void kernel_launch(void* const* d_in, const int* in_sizes, int n_in,
                              void* d_out, int out_size, void* d_ws, size_t ws_size,
                              hipStream_t stream) {
    const float* x  = (const float*)d_in[0];
    // d_in[1] = temb (unused by reference)
    const float* Wq = (const float*)d_in[2];
    const float* bq = (const float*)d_in[3];
    const float* Wk = (const float*)d_in[4];
    const float* bk = (const float*)d_in[5];
    const float* Wv = (const float*)d_in[6];
    const float* bv = (const float*)d_in[7];
    const float* Wo = (const float*)d_in[8];
    const float* bo = (const float*)d_in[9];
    float* out = (float*)d_out;

    char* ws = (char*)d_ws;
    float*  partial = (float*)ws;                       // 512 floats
    float*  stats   = (float*)(ws + 2048);              // 16 floats
    short*  q   = (short*)(ws + 4096);                  // [B][S][C] bf16 (4 MB)
    char*   kt  = (char*)(q + (size_t)B_ * S_ * C_);    // [B][64][8192] swizzled K (4 MB)
    char*   vt  = kt + (size_t)B_ * 64 * 8192;          // [B][64][8192] swizzled V^T (4 MB)
    short*  op  = (short*)(vt + (size_t)B_ * 64 * 8192);// [2][B][S][C] bf16 partials (8 MB)
    float2* mlp = (float2*)((char*)op + (size_t)2 * B_ * S_ * C_ * 2); // [2][B][S] (512 KB)

    stats1_kernel<<<256, 256, 0, stream>>>(x, partial);
    stats2_kernel<<<1, 512, 0, stream>>>(partial, stats);
    proj_kernel<<<B_ * (S_ / 64), 256, 0, stream>>>(x, Wq, bq, Wk, bk, Wv, bv, stats, q, kt, vt);
    flash_kernel<<<B_ * (S_ / 64) * 2, 256, 0, stream>>>(q, kt, vt, op, mlp);
    combine_kernel<<<B_ * (S_ / 64), 256, 0, stream>>>(op, mlp, Wo, bo, x, out);
}

// Round 13
// 91.546 us; speedup vs baseline: 1.6137x; 1.1514x over previous
//
#include <hip/hip_runtime.h>
#include <hip/hip_bf16.h>
#include <math.h>

#define B_ 8
#define S_ 4096
#define C_ 64
#define EPSV 1e-5f

using floatx4 = __attribute__((ext_vector_type(4))) float;
using bf16x8  = __attribute__((ext_vector_type(8))) short;
using bf16x4  = __attribute__((ext_vector_type(4))) short;

typedef __attribute__((address_space(3))) unsigned int       as3_u32;
typedef __attribute__((address_space(1))) const unsigned int as1_u32;

__device__ __forceinline__ short f2bf(float f) {
    unsigned u = __builtin_bit_cast(unsigned, f);
    u = u + 0x7fffu + ((u >> 16) & 1u);   // RNE
    return (short)(u >> 16);
}

__device__ __forceinline__ float bf2f(short s) {
    return __builtin_bit_cast(float, ((unsigned)(unsigned short)s) << 16);
}

__device__ __forceinline__ unsigned cvt_pk_bf16(float lo, float hi) {
    unsigned r;
    asm volatile("v_cvt_pk_bf16_f32 %0, %1, %2" : "=v"(r) : "v"(lo), "v"(hi));
    return r;
}

// PV MFMA: 16x16x16 bf16 (K=16) — B-fragment layout (col=c, k=4g+j) matches
// the swapped-QK^T accumulator layout directly -> no cross-lane redistribution.
__device__ __forceinline__ floatx4 mfma_16x16x16_bf16(bf16x4 a, bf16x4 b, floatx4 c) {
#if __has_builtin(__builtin_amdgcn_mfma_f32_16x16x16bf16_1k)
    return __builtin_amdgcn_mfma_f32_16x16x16bf16_1k(a, b, c, 0, 0, 0);
#else
    asm("v_mfma_f32_16x16x16_bf16 %0, %1, %2, %0" : "+v"(c) : "v"(a), "v"(b));
    return c;
#endif
}

// B-fragment from a row-major fp32 64x64 weight matrix.
__device__ __forceinline__ bf16x8 ld_w_frag(const float* __restrict__ W, int n, int kk, int g, int c) {
    const float* p = W + (16 * n + c) * C_ + 32 * kk + 8 * g;
    bf16x8 r;
#pragma unroll
    for (int j = 0; j < 8; ++j) r[j] = f2bf(p[j]);
    return r;
}

// ---------------- kernel 1a: per-chunk partial sums ----------------
__global__ __launch_bounds__(256) void stats1_kernel(const float* __restrict__ x,
                                                     float* __restrict__ partial) {
    int b = blockIdx.x >> 5, chunk = blockIdx.x & 31;
    const float4* xb = (const float4*)x + (size_t)b * 65536 + chunk * 2048;
    float s = 0.f, ss = 0.f;
#pragma unroll
    for (int i = 0; i < 8; ++i) {
        float4 v = xb[threadIdx.x + i * 256];
        s  += v.x + v.y + v.z + v.w;
        ss += v.x * v.x + v.y * v.y + v.z * v.z + v.w * v.w;
    }
    for (int off = 32; off > 0; off >>= 1) {
        s  += __shfl_down(s, off);
        ss += __shfl_down(ss, off);
    }
    __shared__ float sm[4], ssm[4];
    int wid = threadIdx.x >> 6, lane = threadIdx.x & 63;
    if (lane == 0) { sm[wid] = s; ssm[wid] = ss; }
    __syncthreads();
    if (threadIdx.x == 0) {
        partial[blockIdx.x * 2]     = sm[0] + sm[1] + sm[2] + sm[3];
        partial[blockIdx.x * 2 + 1] = ssm[0] + ssm[1] + ssm[2] + ssm[3];
    }
}

// ---------------- kernel 1b: finalize mean / rsqrt(var) ----------------
__global__ __launch_bounds__(512) void stats2_kernel(const float* __restrict__ partial,
                                                     float* __restrict__ stats) {
    int w = threadIdx.x >> 6, lane = threadIdx.x & 63;  // wave w = batch w
    float s = 0.f, ss = 0.f;
    if (lane < 32) {
        s  = partial[(w * 32 + lane) * 2];
        ss = partial[(w * 32 + lane) * 2 + 1];
    }
    for (int off = 16; off > 0; off >>= 1) {
        s  += __shfl_down(s, off);
        ss += __shfl_down(ss, off);
    }
    if (lane == 0) {
        const float invN = 1.0f / (float)(S_ * C_);
        float mu  = s * invN;
        float var = ss * invN - mu * mu;
        stats[w * 2]     = mu;
        stats[w * 2 + 1] = rsqrtf(var + EPSV);
    }
}

// ---------------- kernel 2: normalize + Q/K/V^T projections ----------------
// K and V^T are written as per-64-kv TILE IMAGES (8192 B each), XOR-swizzled
// exactly as the flash kernel's LDS wants them (both-sides rule).
//   K tile:  [64 kv-rows][64 ch] bf16, byte = (r*128 + ch*2) ^ ((r&7)<<4)
//   V tile:  [64 ch-rows][64 kv] bf16, byte = (ch*128 + u*2) ^ ((ch&7)<<4)
__global__ __launch_bounds__(256) void proj_kernel(
    const float* __restrict__ x,
    const float* __restrict__ Wq, const float* __restrict__ bq,
    const float* __restrict__ Wk, const float* __restrict__ bk,
    const float* __restrict__ Wv, const float* __restrict__ bv,
    const float* __restrict__ stats,
    short* __restrict__ qo, char* __restrict__ kws, char* __restrict__ vws) {
    __shared__ char hbuf[64 * 128];  // [64 rows][64 bf16], XOR-swizzled

    int b  = blockIdx.x >> 6;
    int t_ = blockIdx.x & 63;        // 64-row tile index within batch
    int s0 = t_ * 64;
    float mu = stats[b * 2], rs = stats[b * 2 + 1];
    const float* xt = x + ((size_t)b * S_ + s0) * C_;
    int t = threadIdx.x;

#pragma unroll
    for (int i = 0; i < 4; ++i) {
        int fi  = t + 256 * i;       // float4 index within 64x64 tile
        int row = fi >> 4;
        int c4  = fi & 15;
        float4 v = *(const float4*)(xt + row * C_ + c4 * 4);
        unsigned lo = (unsigned)(unsigned short)f2bf((v.x - mu) * rs) |
                      ((unsigned)(unsigned short)f2bf((v.y - mu) * rs) << 16);
        unsigned hi = (unsigned)(unsigned short)f2bf((v.z - mu) * rs) |
                      ((unsigned)(unsigned short)f2bf((v.w - mu) * rs) << 16);
        int off = row * 128 + c4 * 8;
        off ^= (row & 7) << 4;
        *(uint2*)(hbuf + off) = make_uint2(lo, hi);
    }
    __syncthreads();

    int lane = t & 63, w = t >> 6;
    int g = lane >> 4, c = lane & 15;

    auto ld_h = [&](int row, int kcol) -> bf16x8 {
        int off = row * 128 + kcol * 2;
        off ^= (row & 7) << 4;
        return *(const bf16x8*)(hbuf + off);
    };

    size_t tilebase = ((size_t)b * 64 + t_) * 8192;

    // ---- Q and K: D = h @ W^T.  A = h rows 16w..16w+15 ----
    bf16x8 ha[2];
    ha[0] = ld_h(16 * w + c, 8 * g);
    ha[1] = ld_h(16 * w + c, 32 + 8 * g);

    const float QSC = 0.125f * 1.44269504088896340736f;  // C^-0.5 * log2(e)

#pragma unroll
    for (int n = 0; n < 4; ++n) {
        floatx4 aq = {0.f, 0.f, 0.f, 0.f}, ak = {0.f, 0.f, 0.f, 0.f};
#pragma unroll
        for (int kk = 0; kk < 2; ++kk) {
            bf16x8 wq = ld_w_frag(Wq, n, kk, g, c);
            bf16x8 wk = ld_w_frag(Wk, n, kk, g, c);
            aq = __builtin_amdgcn_mfma_f32_16x16x32_bf16(ha[kk], wq, aq, 0, 0, 0);
            ak = __builtin_amdgcn_mfma_f32_16x16x32_bf16(ha[kk], wk, ak, 0, 0, 0);
        }
        float bqv = bq[16 * n + c], bkv = bk[16 * n + c];
#pragma unroll
        for (int r = 0; r < 4; ++r) {
            int rr = 16 * w + 4 * g + r;          // kv row within tile
            qo[((size_t)b * S_ + s0 + rr) * C_ + 16 * n + c] = f2bf((aq[r] + bqv) * QSC);
            int koff = (rr * 128 + (16 * n + c) * 2) ^ ((rr & 7) << 4);
            *(short*)(kws + tilebase + koff) = f2bf(ak[r] + bkv);
        }
    }

    // ---- V^T = Wv @ h^T (direct transposed, swizzled tile image) ----
    bf16x8 wv[2];
    wv[0] = ld_w_frag(Wv, w, 0, g, c);
    wv[1] = ld_w_frag(Wv, w, 1, g, c);
    float bvr[4];
#pragma unroll
    for (int r = 0; r < 4; ++r) bvr[r] = bv[16 * w + 4 * g + r];

#pragma unroll
    for (int n = 0; n < 4; ++n) {
        floatx4 av = {0.f, 0.f, 0.f, 0.f};
#pragma unroll
        for (int kk = 0; kk < 2; ++kk) {
            bf16x8 hb = ld_h(16 * n + c, 32 * kk + 8 * g);
            av = __builtin_amdgcn_mfma_f32_16x16x32_bf16(wv[kk], hb, av, 0, 0, 0);
        }
#pragma unroll
        for (int r = 0; r < 4; ++r) {
            int rr = 16 * w + 4 * g + r;          // channel row
            int u  = 16 * n + c;                  // kv col within tile
            int voff = (rr * 128 + u * 2) ^ ((rr & 7) << 4);
            *(short*)(vws + tilebase + voff) = f2bf(av[r] + bvr[r]);
        }
    }
}

// ---------------- kernel 3: low-register KV-split flash attention ----------------
// Grid 1024: block = (batch, 64-q-tile, kv-half). 4 waves; wave w owns q rows
// q0+16w..+15 COMPLETELY (own m/l/oacc: ~60 unified regs -> no AGPR occupancy
// cap, the R7-R12 hidden limiter). 32 tiles per block, LDS 32KB double-buffer
// -> 4 blocks/CU x 4 waves = 16 waves/CU, first real residency doubling.
// Output: unnormalized bf16 partial O + per-q (M,L); combine kernel merges.
__global__ __launch_bounds__(256) void flash_kernel(
    const short* __restrict__ qm, const char* __restrict__ kws, const char* __restrict__ vws,
    short* __restrict__ Opart, float2* __restrict__ mlpart) {
    __shared__ char lds[32768];   // [0,16K): K dbuf; [16K,32K): V dbuf

    int bid = blockIdx.x;
    int logical = (bid & 7) * 128 + (bid >> 3);  // XCD swizzle: batch b -> XCD b
    int b = logical >> 7;
    int rest = logical & 127;
    int q0 = (rest >> 1) * 64;
    int half = rest & 1;
    int t = threadIdx.x;
    int lane = t & 63, w = t >> 6;
    int g = lane >> 4, c = lane & 15;
    int qw = q0 + 16 * w;

    const char* kbase = kws + (size_t)b * 64 * 8192;
    const char* vbase = vws + (size_t)b * 64 * 8192;
    const short* qp = qm + (size_t)b * S_ * C_;

    // Q^T B-fragments (this wave's 16 q rows only): lane reads q row (qw+c)
    bf16x8 bqf[2];
    bqf[0] = *(const bf16x8*)(qp + (qw + c) * C_ + 8 * g);
    bqf[1] = *(const bf16x8*)(qp + (qw + c) * C_ + 32 + 8 * g);

    floatx4 oacc[4];
#pragma unroll
    for (int n = 0; n < 4; ++n) oacc[n] = (floatx4){0.f, 0.f, 0.f, 0.f};
    float m = -__builtin_inff(), lsum = 0.f;

    const int xmask = (c & 7) << 4;   // per-lane row-swizzle mask (bits 4-6)

    auto STAGE = [&](int bi, int tt) {
        const char* gk = kbase + (size_t)tt * 8192 + w * 2048 + lane * 16;
        const char* gv = vbase + (size_t)tt * 8192 + w * 2048 + lane * 16;
        char* lk = lds +         bi * 8192 + w * 2048 + lane * 16;
        char* lv = lds + 16384 + bi * 8192 + w * 2048 + lane * 16;
        __builtin_amdgcn_global_load_lds((as1_u32*)gk,          (as3_u32*)lk,          16, 0, 0);
        __builtin_amdgcn_global_load_lds((as1_u32*)(gk + 1024), (as3_u32*)(lk + 1024), 16, 0, 0);
        __builtin_amdgcn_global_load_lds((as1_u32*)gv,          (as3_u32*)lv,          16, 0, 0);
        __builtin_amdgcn_global_load_lds((as1_u32*)(gv + 1024), (as3_u32*)(lv + 1024), 16, 0, 0);
    };

    // swizzled K read: row = 16*subtile + c, column bytes colb (16B granule)
    auto ld_k = [&](const char* buf, int subtile, int colb) -> bf16x8 {
        return *(const bf16x8*)(buf + subtile * 2048 + c * 128 + (colb ^ xmask));
    };
    // swizzled V read (8B): row = 16*mi + c (channel), kv chunk = 16*s + 4*g
    auto ld_v = [&](const char* buf, int mi, int s) -> bf16x4 {
        return *(const bf16x4*)(buf + mi * 2048 + c * 128 + ((32 * s + 8 * g) ^ xmask));
    };

    auto COMPUTE = [&](int bi) {
        const char* kbuf = lds +         bi * 8192;
        const char* vbuf = lds + 16384 + bi * 8192;
        // ---- S^T (64 kv x 16 q) = K @ Q^T ----
        floatx4 st[4];
        __builtin_amdgcn_s_setprio(1);
#pragma unroll
        for (int s = 0; s < 4; ++s) {
            st[s] = (floatx4){0.f, 0.f, 0.f, 0.f};
#pragma unroll
            for (int kk = 0; kk < 2; ++kk) {
                bf16x8 ak = ld_k(kbuf, s, 64 * kk + 16 * g);
                st[s] = __builtin_amdgcn_mfma_f32_16x16x32_bf16(ak, bqf[kk], st[s], 0, 0, 0);
            }
        }
        __builtin_amdgcn_s_setprio(0);
        // ---- online softmax (q = qw + c per lane; log2-domain scores) ----
        float mt = st[0][0];
#pragma unroll
        for (int s = 0; s < 4; ++s)
#pragma unroll
            for (int r = 0; r < 4; ++r) mt = fmaxf(mt, st[s][r]);
        mt = fmaxf(mt, __shfl_xor(mt, 16));
        mt = fmaxf(mt, __shfl_xor(mt, 32));
        // defer-max (T13): skip rescale unless max grew by > 8 (p bounded by 2^8)
        if (!__all(mt - m <= 8.0f)) {
            float mnew  = fmaxf(m, mt);
            float alpha = __builtin_amdgcn_exp2f(m - mnew);
            lsum *= alpha;
            m = mnew;
#pragma unroll
            for (int n = 0; n < 4; ++n) oacc[n] *= alpha;
        }
        bf16x4 pb[4];
        float psum = 0.f;
#pragma unroll
        for (int s = 0; s < 4; ++s) {
            float e0 = __builtin_amdgcn_exp2f(st[s][0] - m);
            float e1 = __builtin_amdgcn_exp2f(st[s][1] - m);
            float e2 = __builtin_amdgcn_exp2f(st[s][2] - m);
            float e3 = __builtin_amdgcn_exp2f(st[s][3] - m);
            psum += (e0 + e1) + (e2 + e3);
            uint2 u = make_uint2(cvt_pk_bf16(e0, e1), cvt_pk_bf16(e2, e3));
            pb[s] = __builtin_bit_cast(bf16x4, u);
        }
        lsum += psum;
        // ---- O^T += V^T @ P^T (16 x 16x16x16 MFMA, B = pb[s] direct) ----
        __builtin_amdgcn_s_setprio(1);
#pragma unroll
        for (int s = 0; s < 4; ++s) {
#pragma unroll
            for (int mi = 0; mi < 4; ++mi) {
                bf16x4 av = ld_v(vbuf, mi, s);
                oacc[mi] = mfma_16x16x16_bf16(av, pb[s], oacc[mi]);
            }
        }
        __builtin_amdgcn_s_setprio(0);
    };

    const int base = half * 32;
    STAGE(0, base);
    __syncthreads();
    for (int r = 0; r < 32; r += 2) {
        STAGE(1, base + r + 1);
        COMPUTE(0);
        __syncthreads();
        if (r + 2 < 32) STAGE(0, base + r + 2);
        COMPUTE(1);
        __syncthreads();
    }

    // ---- finalize: l reduce across lane groups; write (M,L) + bf16 partial ----
    lsum += __shfl_xor(lsum, 16);
    lsum += __shfl_xor(lsum, 32);

    size_t prow = (size_t)(half * 8 + b) * S_ + q0;
    if (lane < 16)
        mlpart[prow + 16 * w + lane] = make_float2(m, lsum);

    short* op = Opart + (prow + 16 * w + c) * C_;
#pragma unroll
    for (int mi = 0; mi < 4; ++mi) {
        uint2 u = make_uint2(cvt_pk_bf16(oacc[mi][0], oacc[mi][1]),
                             cvt_pk_bf16(oacc[mi][2], oacc[mi][3]));
        *(uint2*)(op + 16 * mi + 4 * g) = u;
    }
}

// ---------------- kernel 4: 2-way LSE combine + Wo + residual ----------------
__global__ __launch_bounds__(256) void combine_kernel(
    const short* __restrict__ Opart, const float2* __restrict__ mlpart,
    const float* __restrict__ Wo, const float* __restrict__ bo,
    const float* __restrict__ x, float* __restrict__ out) {
    __shared__ char obuf[8192];   // [64 q][64 ch] bf16, XOR-swizzled

    int bid = blockIdx.x;
    int logical = (bid & 7) * 64 + (bid >> 3);  // XCD swizzle: batch b -> XCD b
    int b = logical >> 6;
    int q0 = (logical & 63) * 64;
    int t = threadIdx.x;
    int lane = t & 63, w = t >> 6;
    int g = lane >> 4, c = lane & 15;

    const short*  P0  = Opart  + ((size_t)b * S_ + q0) * C_;
    const short*  P1  = Opart  + ((size_t)(8 + b) * S_ + q0) * C_;
    const float2* ml0 = mlpart + (size_t)b * S_ + q0;
    const float2* ml1 = mlpart + (size_t)(8 + b) * S_ + q0;

#pragma unroll
    for (int i = 0; i < 16; ++i) {
        int idx = t + 256 * i;
        int q = idx >> 6, ch = idx & 63;
        float2 a0 = ml0[q], a1 = ml1[q];
        float M  = fmaxf(a0.x, a1.x);
        float s0 = __builtin_amdgcn_exp2f(a0.x - M);
        float s1 = __builtin_amdgcn_exp2f(a1.x - M);
        float L  = a0.y * s0 + a1.y * s1;
        float o  = (bf2f(P0[q * 64 + ch]) * s0 + bf2f(P1[q * 64 + ch]) * s1) / L;
        int off = (q * 128 + ch * 2) ^ ((q & 7) << 4);
        *(short*)(obuf + off) = f2bf(o);
    }
    __syncthreads();

    // wave w handles q rows q0+16w..+15; out = o @ Wo^T + bo + x
    bf16x8 ao[2];
    {
        int row = 16 * w + c;
        int off0 = (row * 128 + (8 * g) * 2)      ^ ((row & 7) << 4);
        int off1 = (row * 128 + (32 + 8 * g) * 2) ^ ((row & 7) << 4);
        ao[0] = *(const bf16x8*)(obuf + off0);
        ao[1] = *(const bf16x8*)(obuf + off1);
    }
#pragma unroll
    for (int n = 0; n < 4; ++n) {
        floatx4 a = {0.f, 0.f, 0.f, 0.f};
#pragma unroll
        for (int kk = 0; kk < 2; ++kk) {
            bf16x8 bw = ld_w_frag(Wo, n, kk, g, c);
            a = __builtin_amdgcn_mfma_f32_16x16x32_bf16(ao[kk], bw, a, 0, 0, 0);
        }
        float bov = bo[16 * n + c];
#pragma unroll
        for (int r = 0; r < 4; ++r) {
            int srow = q0 + 16 * w + 4 * g + r;
            size_t idx = ((size_t)b * S_ + srow) * C_ + 16 * n + c;
            out[idx] = x[idx] + bov + a[r];
        }
    }
}

extern "C" void kernel_launch(void* const* d_in, const int* in_sizes, int n_in,
                              void* d_out, int out_size, void* d_ws, size_t ws_size,
                              hipStream_t stream) {
    const float* x  = (const float*)d_in[0];
    // d_in[1] = temb (unused by reference)
    const float* Wq = (const float*)d_in[2];
    const float* bq = (const float*)d_in[3];
    const float* Wk = (const float*)d_in[4];
    const float* bk = (const float*)d_in[5];
    const float* Wv = (const float*)d_in[6];
    const float* bv = (const float*)d_in[7];
    const float* Wo = (const float*)d_in[8];
    const float* bo = (const float*)d_in[9];
    float* out = (float*)d_out;

    char* ws = (char*)d_ws;
    float*  partial = (float*)ws;                       // 512 floats
    float*  stats   = (float*)(ws + 2048);              // 16 floats
    short*  q   = (short*)(ws + 4096);                  // [B][S][C] bf16 (4 MB)
    char*   kt  = (char*)(q + (size_t)B_ * S_ * C_);    // [B][64][8192] swizzled K (4 MB)
    char*   vt  = kt + (size_t)B_ * 64 * 8192;          // [B][64][8192] swizzled V^T (4 MB)
    short*  op  = (short*)(vt + (size_t)B_ * 64 * 8192);// [2][B][S][C] bf16 partials (8 MB)
    float2* mlp = (float2*)((char*)op + (size_t)2 * B_ * S_ * C_ * 2); // [2][B][S] (512 KB)

    stats1_kernel<<<256, 256, 0, stream>>>(x, partial);
    stats2_kernel<<<1, 512, 0, stream>>>(partial, stats);
    proj_kernel<<<B_ * (S_ / 64), 256, 0, stream>>>(x, Wq, bq, Wk, bk, Wv, bv, stats, q, kt, vt);
    flash_kernel<<<B_ * (S_ / 64) * 2, 256, 0, stream>>>(q, kt, vt, op, mlp);
    combine_kernel<<<B_ * (S_ / 64), 256, 0, stream>>>(op, mlp, Wo, bo, x, out);
}